// Round 6
// baseline (302.506 us; speedup 1.0000x reference)
//
#include <hip/hip_runtime.h>
#include <stdint.h>

#define TT 4096
#define HIDD 1024

typedef __attribute__((ext_vector_type(4))) float f32x4;
typedef __attribute__((ext_vector_type(8))) short s16x8;

static constexpr float kEps = 1e-6f;
static constexpr float kCsc = 0.125f * 1.44269504088896f;  // scale * log2(e), folded into q

// ---- workspace layout (bytes) ----
static constexpr size_t OFF_HS   = 0;          // bf16 hs swz   [4096][1024]  8 MB
static constexpr size_t OFF_WQKV = 8388608;    // bf16 WqkvT swz [1536][1024] 3 MB
static constexpr size_t OFF_WO   = 11534336;   // bf16 WoT swz  [1024][1024]  2 MB
static constexpr size_t OFF_QKV  = 13631488;   // f32 qkv       [4096][1536] 24 MB
static constexpr size_t OFF_Q    = 0;          // bf16 q  [16][4096][64] (reuse HS)
static constexpr size_t OFF_K    = 8388608;    // bf16 k plain [4][4096][64] (reuse WQKV)
static constexpr size_t OFF_VT   = 38797312;   // bf16 vT tiled [4][64][64d][64t] 2 MB
static constexpr size_t OFF_O    = 13631488;   // bf16 attn-out swz [4096][1024] (reuse QKV)

__device__ __forceinline__ unsigned int pk_bf16(float a, float b) {
  union { float f; unsigned int u; } x, y;
  x.f = a; y.f = b;
  unsigned int lo = (x.u + 0x7fffu + ((x.u >> 16) & 1u)) >> 16;
  unsigned int hi = (y.u + 0x7fffu + ((y.u >> 16) & 1u)) >> 16;
  return (lo & 0xffffu) | (hi << 16);
}
__device__ __forceinline__ unsigned short bf16_1(float a) {
  union { float f; unsigned int u; } x; x.f = a;
  return (unsigned short)((x.u + 0x7fffu + ((x.u >> 16) & 1u)) >> 16);
}
__device__ __forceinline__ unsigned int cvtpk(float lo, float hi) {
  unsigned int r;
  asm("v_cvt_pk_bf16_f32 %0, %1, %2" : "=v"(r) : "v"(lo), "v"(hi));
  return r;
}
__device__ __forceinline__ float fexp2(float x) {
  float r;
  asm("v_exp_f32 %0, %1\n\ts_nop 0" : "=v"(r) : "v"(x));
  return r;
}
__device__ __forceinline__ void gload16(const void* g, void* l) {
  __builtin_amdgcn_global_load_lds(
      (const __attribute__((address_space(1))) unsigned int*)g,
      (__attribute__((address_space(3))) unsigned int*)l, 16, 0, 0);
}

// hs fp32 [T][1024] -> bf16 swizzled (16B chunk index XORed by row&7 within 64-elem groups)
__global__ void k_convert_hs(const float* __restrict__ hs, unsigned short* __restrict__ out) {
  int idx = blockIdx.x * 256 + threadIdx.x;  // T*128
  int t = idx >> 7, kc = idx & 127;
  const float4* src = (const float4*)(hs + (size_t)t * HIDD + kc * 8);
  float4 a = src[0], b = src[1];
  int kcs = (kc & ~7) | ((kc & 7) ^ (t & 7));
  uint4 w;
  w.x = pk_bf16(a.x, a.y); w.y = pk_bf16(a.z, a.w);
  w.z = pk_bf16(b.x, b.y); w.w = pk_bf16(b.z, b.w);
  *(uint4*)(out + (size_t)t * HIDD + kcs * 8) = w;
}

// All four weight matrices: fp32 [1024][ncols] -> bf16 W^T [ncols][1024] swizzled by n&7
__global__ void k_convert_w_all(const float* __restrict__ Wq, const float* __restrict__ Wk,
                                const float* __restrict__ Wv, const float* __restrict__ Wo,
                                unsigned short* __restrict__ wqkv, unsigned short* __restrict__ wo_t) {
  int b = blockIdx.x, tid = threadIdx.x;
  const float* W; unsigned short* outT; int nshift, idx;
  if (b < 512)      { W = Wq; outT = wqkv;                nshift = 10; idx = b * 256 + tid; }
  else if (b < 640) { W = Wk; outT = wqkv + 1024 * 1024;  nshift = 8;  idx = (b - 512) * 256 + tid; }
  else if (b < 768) { W = Wv; outT = wqkv + 1280 * 1024;  nshift = 8;  idx = (b - 640) * 256 + tid; }
  else              { W = Wo; outT = wo_t;                nshift = 10; idx = (b - 768) * 256 + tid; }
  int ncols = 1 << nshift;
  int kc = idx >> nshift, n = idx & (ncols - 1);
  float v[8];
#pragma unroll
  for (int e = 0; e < 8; ++e) v[e] = W[(size_t)(kc * 8 + e) * ncols + n];
  int kcs = (kc & ~7) | ((kc & 7) ^ (n & 7));
  uint4 w;
  w.x = pk_bf16(v[0], v[1]); w.y = pk_bf16(v[2], v[3]);
  w.z = pk_bf16(v[4], v[5]); w.w = pk_bf16(v[6], v[7]);
  *(uint4*)(outT + (size_t)n * HIDD + kcs * 8) = w;
}

// C[M][N] = A[M][K] * Bt[N][K]^T ; A,Bt bf16 chunk-swizzled; C fp32.
// 128x128 tile, BK=64, 8 waves (2x4), double-buffered LDS, one barrier per K-step.
__global__ __launch_bounds__(512) void k_gemm(const unsigned short* __restrict__ A,
                                              const unsigned short* __restrict__ Bt,
                                              float* __restrict__ C, int M, int N, int K) {
  __shared__ __attribute__((aligned(16))) unsigned short As[2][128 * 64];
  __shared__ __attribute__((aligned(16))) unsigned short Bs[2][128 * 64];
  const int tid = threadIdx.x;
  const int m0 = blockIdx.y * 128, n0 = blockIdx.x * 128;
  const int wid = tid >> 6, lane = tid & 63;
  const int g = lane >> 4, qi = lane & 15;
  const int wr = wid >> 2, wc = wid & 3;
  const int srow = tid >> 3, schk = tid & 7;
  f32x4 acc[4][2] = {};
  const int nkt = K >> 6;

  auto STAGE = [&](int b, int k0) {
#pragma unroll
    for (int j = 0; j < 2; ++j) {
      int ra = j * 64 + srow;
      gload16(A + (size_t)(m0 + ra) * K + k0 + schk * 8,
              (char*)&As[b][0] + j * 8192 + (wid << 10));
      gload16(Bt + (size_t)(n0 + ra) * K + k0 + schk * 8,
              (char*)&Bs[b][0] + j * 8192 + (wid << 10));
    }
  };

  STAGE(0, 0);
  __syncthreads();
  int cur = 0;
  for (int kt = 0; kt < nkt; ++kt) {
    if (kt + 1 < nkt) STAGE(cur ^ 1, (kt + 1) << 6);
#pragma unroll
    for (int kh = 0; kh < 2; ++kh) {
      s16x8 af[4], bq[2];
#pragma unroll
      for (int i = 0; i < 4; ++i) {
        int rA = wr * 64 + i * 16 + qi;
        af[i] = *(const s16x8*)((const char*)&As[cur][0] + rA * 128 + ((((kh << 2) | g) ^ (rA & 7)) << 4));
      }
#pragma unroll
      for (int jn = 0; jn < 2; ++jn) {
        int rB = wc * 32 + jn * 16 + qi;
        bq[jn] = *(const s16x8*)((const char*)&Bs[cur][0] + rB * 128 + ((((kh << 2) | g) ^ (rB & 7)) << 4));
      }
      __builtin_amdgcn_s_setprio(1);
#pragma unroll
      for (int i = 0; i < 4; ++i)
#pragma unroll
        for (int jn = 0; jn < 2; ++jn)
          acc[i][jn] = __builtin_amdgcn_mfma_f32_16x16x32_bf16(af[i], bq[jn], acc[i][jn], 0, 0, 0);
      __builtin_amdgcn_s_setprio(0);
    }
    __syncthreads();
    cur ^= 1;
  }
#pragma unroll
  for (int i = 0; i < 4; ++i)
#pragma unroll
    for (int jn = 0; jn < 2; ++jn) {
      int row = m0 + wr * 64 + i * 16 + g * 4;
      int col = n0 + wc * 32 + jn * 16 + qi;
#pragma unroll
      for (int r = 0; r < 4; ++r)
        C[(size_t)(row + r) * N + col] = acc[i][jn][r];
    }
}

// RMSNorm + RoPE for q (slots 0..15) and k (slots 16..19). One wave per (t,slot).
// q pre-scaled by 0.125*log2(e). k now stored PLAIN [hv][t][d] (attn reads L2-direct).
__global__ void k_prep(const float* __restrict__ qkv, const float* __restrict__ cosb,
                       const float* __restrict__ sinb, const float* __restrict__ qw,
                       const float* __restrict__ kw, unsigned short* __restrict__ qo,
                       unsigned short* __restrict__ ko) {
  int rowid = blockIdx.x * 4 + (threadIdx.x >> 6);
  int lane = threadIdx.x & 63;
  int t = rowid / 20, slot = rowid % 20;
  float x = qkv[(size_t)t * 1536 + slot * 64 + lane];
  float ss = x * x;
#pragma unroll
  for (int off = 32; off; off >>= 1) ss += __shfl_xor(ss, off);
  float n = x * rsqrtf(ss * (1.0f / 64.0f) + kEps);
  n *= (slot < 16) ? qw[lane] : kw[lane];
  float c = cosb[t * 32 + (lane & 31)];
  float s = sinb[t * 32 + (lane & 31)];
  float other = __shfl_xor(n, 32);
  float r = (lane < 32) ? (n * c - other * s) : (other * s + n * c);
  if (slot < 16) {
    unsigned short b = bf16_1(r * kCsc);
    qo[((size_t)slot * TT + t) * 64 + lane] = b;   // linear [h][t][d]
  } else {
    unsigned short b = bf16_1(r);
    int hv = slot - 16;
    ko[((size_t)hv * TT + t) * 64 + lane] = b;     // plain [hv][t][d]
  }
}

// v: qkv fp32 [t][1280+hv*64+d] -> bf16 vT tiled [hv][blk][d][64t] (plain, no swizzle)
__global__ void k_vT(const float* __restrict__ qkv, unsigned short* __restrict__ vt) {
  __shared__ float tile[64][65];
  int t0 = blockIdx.x * 64, hv = blockIdx.y, tid = threadIdx.x;
  int blk = blockIdx.x;
  int cc = tid & 63, rr0 = tid >> 6;
#pragma unroll
  for (int i = 0; i < 16; ++i) {
    int r = rr0 * 16 + i;
    tile[r][cc] = qkv[(size_t)(t0 + r) * 1536 + 1280 + hv * 64 + cc];
  }
  __syncthreads();
#pragma unroll
  for (int jj = 0; jj < 2; ++jj) {
    int idx = jj * 256 + tid;
    int d = idx >> 3, tc = idx & 7;
    uint4 w;
    w.x = pk_bf16(tile[tc * 8 + 0][d], tile[tc * 8 + 1][d]);
    w.y = pk_bf16(tile[tc * 8 + 2][d], tile[tc * 8 + 3][d]);
    w.z = pk_bf16(tile[tc * 8 + 4][d], tile[tc * 8 + 5][d]);
    w.w = pk_bf16(tile[tc * 8 + 6][d], tile[tc * 8 + 7][d]);
    *(uint4*)(vt + (((size_t)hv * 64 + blk) * 64 + d) * 64 + tc * 8) = w;
  }
}

// Flash attention, causal GQA — barrier-free. 256 blocks x 8 waves; each wave owns
// the q-tile PAIR (255-a, a) of 16-row tiles processed sequentially (uniform ~66
// steps/wave). K/V read DIRECTLY from L2 into MFMA fragments (KV = 1MB per XCD,
// L2-resident; XCD-chunked decode). P via wave-private swizzled LDS. T15 pipeline:
// K-loads(i) -> SMPV(i-1) -> QK(i). Fixed-max exp2 softmax (v_exp_f32 raw).
__global__ __launch_bounds__(512, 2) void k_attn(const unsigned short* __restrict__ q,
                                                 const unsigned short* __restrict__ kk,
                                                 const unsigned short* __restrict__ vt,
                                                 unsigned short* __restrict__ o) {
  __shared__ __attribute__((aligned(16))) unsigned short Pl[8][1024];
  const int tid = threadIdx.x;
  const int wid = tid >> 6, lane = tid & 63, g = lane >> 4, qi = lane & 15;
  const int bid = blockIdx.x;
  const int xcd = bid & 7, blk = bid >> 3;
  const int p = blk * 8 + wid;               // 0..255 within XCD
  const int head = xcd * 2 + (p >> 7);       // 2 heads per XCD (one KV group)
  const int aa = p & 127;
  const int hv = head >> 2;
  char* pb = (char*)&Pl[wid][0];
  const unsigned short* kb = kk + ((size_t)hv * TT) * 64;

  for (int half = 0; half < 2; ++half) {
    const int t16 = half ? aa : (255 - aa);  // long tile first
    const int nst = (t16 >> 2) + 1;
    const int qg = t16 * 16 + qi;
    s16x8 qf[2];
#pragma unroll
    for (int kh = 0; kh < 2; ++kh)
      qf[kh] = *(const s16x8*)(q + ((size_t)head * TT + qg) * 64 + kh * 32 + g * 8);
    f32x4 acc[4] = {};
    float l0 = 0.0f, l1 = 0.0f;
    float pv[16];

    auto SMPV = [&](int s) {
      const unsigned short* vb = vt + (((size_t)hv * 64 + s) * 64) * 64;
      s16x8 vf[2][4];
#pragma unroll
      for (int kh = 0; kh < 2; ++kh)
#pragma unroll
        for (int cf = 0; cf < 4; ++cf)
          vf[kh][cf] = *(const s16x8*)(vb + (size_t)(cf * 16 + qi) * 64 + kh * 32 + g * 8);
#pragma unroll
      for (int j = 0; j < 8; ++j) {
        float e0 = fexp2(pv[2 * j]), e1 = fexp2(pv[2 * j + 1]);
        pv[2 * j] = e0; pv[2 * j + 1] = e1;
        l0 += e0; l1 += e1;
      }
#pragma unroll
      for (int cf = 0; cf < 4; ++cf) {
        int chunk = cf * 2 + (g >> 1);
        int base = qi * 128 + ((chunk ^ (qi & 7)) << 4) + ((g & 1) << 3);
        uint2 pw;
        pw.x = cvtpk(pv[cf * 4 + 0], pv[cf * 4 + 1]);
        pw.y = cvtpk(pv[cf * 4 + 2], pv[cf * 4 + 3]);
        *(uint2*)(pb + base) = pw;
      }
#pragma unroll
      for (int kh = 0; kh < 2; ++kh) {
        s16x8 pf = *(const s16x8*)(pb + qi * 128 + ((((kh << 2) | g) ^ (qi & 7)) << 4));
        __builtin_amdgcn_s_setprio(1);
#pragma unroll
        for (int cf = 0; cf < 4; ++cf)
          acc[cf] = __builtin_amdgcn_mfma_f32_16x16x32_bf16(vf[kh][cf], pf, acc[cf], 0, 0, 0);
        __builtin_amdgcn_s_setprio(0);
      }
    };

    for (int i = 0; i < nst; ++i) {
      const int kv0 = i * 64;
      // K fragments straight from L2
      s16x8 kf[2][4];
#pragma unroll
      for (int kh = 0; kh < 2; ++kh)
#pragma unroll
        for (int cf = 0; cf < 4; ++cf)
          kf[kh][cf] = *(const s16x8*)(kb + (size_t)(kv0 + cf * 16 + qi) * 64 + kh * 32 + g * 8);
      // overlap: finish previous step's softmax+PV while K loads are in flight
      if (i > 0) SMPV(i - 1);
      f32x4 sacc[4] = {};
#pragma unroll
      for (int kh = 0; kh < 2; ++kh) {
        __builtin_amdgcn_s_setprio(1);
#pragma unroll
        for (int cf = 0; cf < 4; ++cf)
          sacc[cf] = __builtin_amdgcn_mfma_f32_16x16x32_bf16(kf[kh][cf], qf[kh], sacc[cf], 0, 0, 0);
        __builtin_amdgcn_s_setprio(0);
      }
      if (i == nst - 1) {
#pragma unroll
        for (int cf = 0; cf < 4; ++cf)
#pragma unroll
          for (int r = 0; r < 4; ++r) {
            float v = sacc[cf][r];
            pv[cf * 4 + r] = ((kv0 + cf * 16 + g * 4 + r) > qg) ? -1e30f : v;
          }
      } else {
#pragma unroll
        for (int cf = 0; cf < 4; ++cf)
#pragma unroll
          for (int r = 0; r < 4; ++r) pv[cf * 4 + r] = sacc[cf][r];
      }
    }
    SMPV(nst - 1);

    float l_run = l0 + l1;
    l_run += __shfl_xor(l_run, 16);
    l_run += __shfl_xor(l_run, 32);
    float inv = 1.0f / l_run;
#pragma unroll
    for (int cf = 0; cf < 4; ++cf) {
      int col = head * 64 + cf * 16 + g * 4;
      int chunk = col >> 3;
      int chs = (chunk & ~7) | ((chunk & 7) ^ (qg & 7));
      char* ob = (char*)o + (size_t)qg * 2048 + (chs << 4) + ((g & 1) << 3);
      *(unsigned int*)ob = cvtpk(acc[cf][0] * inv, acc[cf][1] * inv);
      *(unsigned int*)(ob + 4) = cvtpk(acc[cf][2] * inv, acc[cf][3] * inv);
    }
  }
}

extern "C" void kernel_launch(void* const* d_in, const int* in_sizes, int n_in,
                              void* d_out, int out_size, void* d_ws, size_t ws_size,
                              hipStream_t stream) {
  const float* hs   = (const float*)d_in[0];
  const float* cosb = (const float*)d_in[1];
  const float* sinb = (const float*)d_in[2];
  const float* Wq   = (const float*)d_in[3];
  const float* Wk   = (const float*)d_in[4];
  const float* Wv   = (const float*)d_in[5];
  const float* Wo   = (const float*)d_in[6];
  const float* qw   = (const float*)d_in[7];
  const float* kw   = (const float*)d_in[8];
  char* ws = (char*)d_ws;
  unsigned short* hs_swz = (unsigned short*)(ws + OFF_HS);
  unsigned short* wqkv   = (unsigned short*)(ws + OFF_WQKV);
  unsigned short* wo_t   = (unsigned short*)(ws + OFF_WO);
  float*          qkv    = (float*)(ws + OFF_QKV);
  unsigned short* qbf    = (unsigned short*)(ws + OFF_Q);
  unsigned short* kbf    = (unsigned short*)(ws + OFF_K);
  unsigned short* vtb    = (unsigned short*)(ws + OFF_VT);
  unsigned short* obf    = (unsigned short*)(ws + OFF_O);

  k_convert_hs<<<2048, 256, 0, stream>>>(hs, hs_swz);
  k_convert_w_all<<<1280, 256, 0, stream>>>(Wq, Wk, Wv, Wo, wqkv, wo_t);
  k_gemm<<<dim3(12, 32), 512, 0, stream>>>(hs_swz, wqkv, qkv, 4096, 1536, 1024);
  k_prep<<<20480, 256, 0, stream>>>(qkv, cosb, sinb, qw, kw, qbf, kbf);
  k_vT<<<dim3(64, 4), 256, 0, stream>>>(qkv, vtb);
  k_attn<<<256, 512, 0, stream>>>(qbf, kbf, vtb, obf);
  k_gemm<<<dim3(8, 32), 512, 0, stream>>>(obf, wo_t, (float*)d_out, 4096, 1024, 1024);
}

// Round 7
// 183.686 us; speedup vs baseline: 1.6469x; 1.6469x over previous
//
#include <hip/hip_runtime.h>
#include <stdint.h>

#define TT 4096
#define HIDD 1024

typedef __attribute__((ext_vector_type(4))) float f32x4;
typedef __attribute__((ext_vector_type(8))) short s16x8;

static constexpr float kEps = 1e-6f;
static constexpr float kCsc = 0.125f * 1.44269504088896f;  // scale * log2(e), folded into q

// ---- workspace layout (bytes) ----
static constexpr size_t OFF_HS   = 0;          // bf16 hs swz   [4096][1024]  8 MB
static constexpr size_t OFF_WQKV = 8388608;    // bf16 WqkvT swz [1536][1024] 3 MB
static constexpr size_t OFF_WO   = 11534336;   // bf16 WoT swz  [1024][1024]  2 MB
static constexpr size_t OFF_QKV  = 13631488;   // f32 qkv       [4096][1536] 24 MB
static constexpr size_t OFF_Q    = 0;          // bf16 q  [16][4096][64] (reuse HS)
static constexpr size_t OFF_K    = 8388608;    // bf16 k swz [4][4096][64] (reuse WQKV)
static constexpr size_t OFF_VT   = 38797312;   // bf16 vT swz [4][64][4096] 2 MB
static constexpr size_t OFF_O    = 13631488;   // bf16 attn-out swz [4096][1024] (reuse QKV)

__device__ __forceinline__ unsigned int pk_bf16(float a, float b) {
  union { float f; unsigned int u; } x, y;
  x.f = a; y.f = b;
  unsigned int lo = (x.u + 0x7fffu + ((x.u >> 16) & 1u)) >> 16;
  unsigned int hi = (y.u + 0x7fffu + ((y.u >> 16) & 1u)) >> 16;
  return (lo & 0xffffu) | (hi << 16);
}
__device__ __forceinline__ unsigned short bf16_1(float a) {
  union { float f; unsigned int u; } x; x.f = a;
  return (unsigned short)((x.u + 0x7fffu + ((x.u >> 16) & 1u)) >> 16);
}
__device__ __forceinline__ unsigned int cvtpk(float lo, float hi) {
  unsigned int r;
  asm("v_cvt_pk_bf16_f32 %0, %1, %2" : "=v"(r) : "v"(lo), "v"(hi));
  return r;
}
__device__ __forceinline__ void gload16(const void* g, void* l) {
  __builtin_amdgcn_global_load_lds(
      (const __attribute__((address_space(1))) unsigned int*)g,
      (__attribute__((address_space(3))) unsigned int*)l, 16, 0, 0);
}

// hs fp32 [T][1024] -> bf16 swizzled (16B chunk index XORed by row&7 within 64-elem groups)
__global__ void k_convert_hs(const float* __restrict__ hs, unsigned short* __restrict__ out) {
  int idx = blockIdx.x * 256 + threadIdx.x;  // T*128
  int t = idx >> 7, kc = idx & 127;
  const float4* src = (const float4*)(hs + (size_t)t * HIDD + kc * 8);
  float4 a = src[0], b = src[1];
  int kcs = (kc & ~7) | ((kc & 7) ^ (t & 7));
  uint4 w;
  w.x = pk_bf16(a.x, a.y); w.y = pk_bf16(a.z, a.w);
  w.z = pk_bf16(b.x, b.y); w.w = pk_bf16(b.z, b.w);
  *(uint4*)(out + (size_t)t * HIDD + kcs * 8) = w;
}

// All four weight matrices: fp32 [1024][ncols] -> bf16 W^T [ncols][1024] swizzled by n&7
__global__ void k_convert_w_all(const float* __restrict__ Wq, const float* __restrict__ Wk,
                                const float* __restrict__ Wv, const float* __restrict__ Wo,
                                unsigned short* __restrict__ wqkv, unsigned short* __restrict__ wo_t) {
  int b = blockIdx.x, tid = threadIdx.x;
  const float* W; unsigned short* outT; int nshift, idx;
  if (b < 512)      { W = Wq; outT = wqkv;                nshift = 10; idx = b * 256 + tid; }
  else if (b < 640) { W = Wk; outT = wqkv + 1024 * 1024;  nshift = 8;  idx = (b - 512) * 256 + tid; }
  else if (b < 768) { W = Wv; outT = wqkv + 1280 * 1024;  nshift = 8;  idx = (b - 640) * 256 + tid; }
  else              { W = Wo; outT = wo_t;                nshift = 10; idx = (b - 768) * 256 + tid; }
  int ncols = 1 << nshift;
  int kc = idx >> nshift, n = idx & (ncols - 1);
  float v[8];
#pragma unroll
  for (int e = 0; e < 8; ++e) v[e] = W[(size_t)(kc * 8 + e) * ncols + n];
  int kcs = (kc & ~7) | ((kc & 7) ^ (n & 7));
  uint4 w;
  w.x = pk_bf16(v[0], v[1]); w.y = pk_bf16(v[2], v[3]);
  w.z = pk_bf16(v[4], v[5]); w.w = pk_bf16(v[6], v[7]);
  *(uint4*)(outT + (size_t)n * HIDD + kcs * 8) = w;
}

// C[M][N] = A[M][K] * Bt[N][K]^T ; A,Bt bf16 chunk-swizzled; C fp32.
// 128x128 tile, BK=64, 8 waves (2x4), double-buffered LDS, one barrier per K-step.
__global__ __launch_bounds__(512) void k_gemm(const unsigned short* __restrict__ A,
                                              const unsigned short* __restrict__ Bt,
                                              float* __restrict__ C, int M, int N, int K) {
  __shared__ __attribute__((aligned(16))) unsigned short As[2][128 * 64];
  __shared__ __attribute__((aligned(16))) unsigned short Bs[2][128 * 64];
  const int tid = threadIdx.x;
  const int m0 = blockIdx.y * 128, n0 = blockIdx.x * 128;
  const int wid = tid >> 6, lane = tid & 63;
  const int g = lane >> 4, qi = lane & 15;
  const int wr = wid >> 2, wc = wid & 3;
  const int srow = tid >> 3, schk = tid & 7;
  f32x4 acc[4][2] = {};
  const int nkt = K >> 6;

  auto STAGE = [&](int b, int k0) {
#pragma unroll
    for (int j = 0; j < 2; ++j) {
      int ra = j * 64 + srow;
      gload16(A + (size_t)(m0 + ra) * K + k0 + schk * 8,
              (char*)&As[b][0] + j * 8192 + (wid << 10));
      gload16(Bt + (size_t)(n0 + ra) * K + k0 + schk * 8,
              (char*)&Bs[b][0] + j * 8192 + (wid << 10));
    }
  };

  STAGE(0, 0);
  __syncthreads();
  int cur = 0;
  for (int kt = 0; kt < nkt; ++kt) {
    if (kt + 1 < nkt) STAGE(cur ^ 1, (kt + 1) << 6);
#pragma unroll
    for (int kh = 0; kh < 2; ++kh) {
      s16x8 af[4], bq[2];
#pragma unroll
      for (int i = 0; i < 4; ++i) {
        int rA = wr * 64 + i * 16 + qi;
        af[i] = *(const s16x8*)((const char*)&As[cur][0] + rA * 128 + ((((kh << 2) | g) ^ (rA & 7)) << 4));
      }
#pragma unroll
      for (int jn = 0; jn < 2; ++jn) {
        int rB = wc * 32 + jn * 16 + qi;
        bq[jn] = *(const s16x8*)((const char*)&Bs[cur][0] + rB * 128 + ((((kh << 2) | g) ^ (rB & 7)) << 4));
      }
      __builtin_amdgcn_s_setprio(1);
#pragma unroll
      for (int i = 0; i < 4; ++i)
#pragma unroll
        for (int jn = 0; jn < 2; ++jn)
          acc[i][jn] = __builtin_amdgcn_mfma_f32_16x16x32_bf16(af[i], bq[jn], acc[i][jn], 0, 0, 0);
      __builtin_amdgcn_s_setprio(0);
    }
    __syncthreads();
    cur ^= 1;
  }
#pragma unroll
  for (int i = 0; i < 4; ++i)
#pragma unroll
    for (int jn = 0; jn < 2; ++jn) {
      int row = m0 + wr * 64 + i * 16 + g * 4;
      int col = n0 + wc * 32 + jn * 16 + qi;
#pragma unroll
      for (int r = 0; r < 4; ++r)
        C[(size_t)(row + r) * N + col] = acc[i][jn][r];
    }
}

// RMSNorm + RoPE for q (slots 0..15) and k (slots 16..19). One wave per (t,slot).
// q pre-scaled by 0.125*log2(e) so attention scores are directly in exp2 domain.
__global__ void k_prep(const float* __restrict__ qkv, const float* __restrict__ cosb,
                       const float* __restrict__ sinb, const float* __restrict__ qw,
                       const float* __restrict__ kw, unsigned short* __restrict__ qo,
                       unsigned short* __restrict__ ko) {
  int rowid = blockIdx.x * 4 + (threadIdx.x >> 6);
  int lane = threadIdx.x & 63;
  int t = rowid / 20, slot = rowid % 20;
  float x = qkv[(size_t)t * 1536 + slot * 64 + lane];
  float ss = x * x;
#pragma unroll
  for (int off = 32; off; off >>= 1) ss += __shfl_xor(ss, off);
  float n = x * rsqrtf(ss * (1.0f / 64.0f) + kEps);
  n *= (slot < 16) ? qw[lane] : kw[lane];
  float c = cosb[t * 32 + (lane & 31)];
  float s = sinb[t * 32 + (lane & 31)];
  float other = __shfl_xor(n, 32);
  float r = (lane < 32) ? (n * c - other * s) : (other * s + n * c);
  if (slot < 16) {
    unsigned short b = bf16_1(r * kCsc);
    qo[((size_t)slot * TT + t) * 64 + lane] = b;   // linear [h][t][d]
  } else {
    unsigned short b = bf16_1(r);
    int hv = slot - 16;
    int d = (((lane >> 3) ^ (t & 7)) << 3) | (lane & 7);  // swizzle chunks by t&7
    ko[((size_t)hv * TT + t) * 64 + d] = b;
  }
}

// v: qkv fp32 [t][1280+hv*64+d] -> bf16 vT [hv][d][t], t-chunks swizzled by d&7
__global__ void k_vT(const float* __restrict__ qkv, unsigned short* __restrict__ vt) {
  __shared__ float tile[64][65];
  int t0 = blockIdx.x * 64, hv = blockIdx.y, tid = threadIdx.x;
  int cc = tid & 63, rr0 = tid >> 6;
#pragma unroll
  for (int i = 0; i < 16; ++i) {
    int r = rr0 * 16 + i;
    tile[r][cc] = qkv[(size_t)(t0 + r) * 1536 + 1280 + hv * 64 + cc];
  }
  __syncthreads();
#pragma unroll
  for (int jj = 0; jj < 2; ++jj) {
    int idx = jj * 256 + tid;
    int d = idx >> 3, tc = idx & 7;
    uint4 w;
    w.x = pk_bf16(tile[tc * 8 + 0][d], tile[tc * 8 + 1][d]);
    w.y = pk_bf16(tile[tc * 8 + 2][d], tile[tc * 8 + 3][d]);
    w.z = pk_bf16(tile[tc * 8 + 4][d], tile[tc * 8 + 5][d]);
    w.w = pk_bf16(tile[tc * 8 + 6][d], tile[tc * 8 + 7][d]);
    int tcs = tc ^ (d & 7);
    *(uint4*)(vt + ((size_t)hv * 64 + d) * TT + t0 + tcs * 8) = w;
  }
}

// Flash attention, causal GQA. R5 structure (staged dbuf K/V, 8 waves = 2 q-tiles/block,
// fixed-max exp2 softmax) + in-wave software pipeline: at step s each wave
// (1) issues K-frag ds_reads for tile s, (2) finishes softmax+PV of tile s-1 (V-frags
// held in registers; order-independent with fixed-max), (3) QK(s) -> raw scores,
// (4) reads V-frags(s) to registers, (5) barrier. Keeps MFMA/VALU/LDS phases of the
// two in-flight tiles overlapped instead of lockstep-aligned.
__global__ __launch_bounds__(512) void k_attn(const unsigned short* __restrict__ q,
                                              const unsigned short* __restrict__ kk,
                                              const unsigned short* __restrict__ vt,
                                              unsigned short* __restrict__ o) {
  __shared__ __attribute__((aligned(16))) unsigned short Kl[2][64 * 64];
  __shared__ __attribute__((aligned(16))) unsigned short Vl[2][64 * 64];
  __shared__ __attribute__((aligned(16))) unsigned short Pl[8][1536];  // 1024 used + pad -> 56KB
  const int tid = threadIdx.x;
  const int bid = blockIdx.x;
  const int work = (bid & 7) * 64 + (bid >> 3);    // XCD-chunked: 2 heads per XCD
  const int h = work >> 5;
  const int i0 = work & 31;
  const int hv = h >> 2;
  const int wid = tid >> 6, lane = tid & 63, g = lane >> 4, qi = lane & 15;
  const int qt = (wid < 4) ? i0 : (63 - i0);       // per-wave q-tile
  const int smax = 63 - i0;
  char* pb = (char*)&Pl[wid][0];

  auto STAGE = [&](int b, int s) {
    const int kv0 = s * 64;
    const int r = wid * 8 + (lane >> 3), c8 = (lane & 7) * 8;
    gload16(kk + ((size_t)hv * TT + kv0 + r) * 64 + c8, (char*)&Kl[b][0] + (wid << 10));
    gload16(vt + ((size_t)hv * 64 + r) * TT + kv0 + c8, (char*)&Vl[b][0] + (wid << 10));
  };

  const int qg = qt * 64 + (wid & 3) * 16 + qi;
  s16x8 qf[2];
#pragma unroll
  for (int kh = 0; kh < 2; ++kh)
    qf[kh] = *(const s16x8*)(q + ((size_t)h * TT + qg) * 64 + kh * 32 + g * 8);
  f32x4 acc[4] = {};
  float l0 = 0.0f, l1 = 0.0f;
  float pv[16];
  s16x8 vf[2][4];

  // finish tile: exp -> P bf16 via wave-private LDS -> PV MFMA (uses vf registers)
  auto SMPV = [&]() {
#pragma unroll
    for (int j = 0; j < 8; ++j) {
      float e0 = exp2f(pv[2 * j]), e1 = exp2f(pv[2 * j + 1]);
      pv[2 * j] = e0; pv[2 * j + 1] = e1;
      l0 += e0; l1 += e1;
    }
#pragma unroll
    for (int cf = 0; cf < 4; ++cf) {
      int chunk = cf * 2 + (g >> 1);
      int base = qi * 128 + ((chunk ^ (qi & 7)) << 4) + ((g & 1) << 3);
      uint2 pw;
      pw.x = cvtpk(pv[cf * 4 + 0], pv[cf * 4 + 1]);
      pw.y = cvtpk(pv[cf * 4 + 2], pv[cf * 4 + 3]);
      *(uint2*)(pb + base) = pw;
    }
#pragma unroll
    for (int kh = 0; kh < 2; ++kh) {
      s16x8 pf = *(const s16x8*)(pb + qi * 128 + ((((kh << 2) | g) ^ (qi & 7)) << 4));
      __builtin_amdgcn_s_setprio(1);
#pragma unroll
      for (int cf = 0; cf < 4; ++cf)
        acc[cf] = __builtin_amdgcn_mfma_f32_16x16x32_bf16(vf[kh][cf], pf, acc[cf], 0, 0, 0);
      __builtin_amdgcn_s_setprio(0);
    }
  };

  STAGE(0, 0);
  __syncthreads();
  int cur = 0;
  for (int s = 0; s <= smax; ++s) {
    if (s < smax) STAGE(cur ^ 1, s + 1);
    s16x8 kf[2][4];
    const bool active = (s <= qt);
    if (active) {
      // issue K-frag reads first so their latency hides under SMPV(s-1)
#pragma unroll
      for (int kh = 0; kh < 2; ++kh)
#pragma unroll
        for (int cf = 0; cf < 4; ++cf) {
          int row = cf * 16 + qi;
          kf[kh][cf] = *(const s16x8*)((const char*)&Kl[cur][0] + row * 128 + ((((kh << 2) | g) ^ (row & 7)) << 4));
        }
    }
    if (s >= 1 && s <= qt + 1) SMPV();   // finish tile s-1
    if (active) {
      const int kv0 = s * 64;
      f32x4 sacc[4] = {};
#pragma unroll
      for (int kh = 0; kh < 2; ++kh) {
        __builtin_amdgcn_s_setprio(1);
#pragma unroll
        for (int cf = 0; cf < 4; ++cf)
          sacc[cf] = __builtin_amdgcn_mfma_f32_16x16x32_bf16(kf[kh][cf], qf[kh], sacc[cf], 0, 0, 0);
        __builtin_amdgcn_s_setprio(0);
      }
      if (s == qt) {
#pragma unroll
        for (int cf = 0; cf < 4; ++cf)
#pragma unroll
          for (int r = 0; r < 4; ++r) {
            float v = sacc[cf][r];
            pv[cf * 4 + r] = ((kv0 + cf * 16 + g * 4 + r) > qg) ? -1e30f : v;
          }
      } else {
#pragma unroll
        for (int cf = 0; cf < 4; ++cf)
#pragma unroll
          for (int r = 0; r < 4; ++r) pv[cf * 4 + r] = sacc[cf][r];
      }
      // V-frags for this tile into registers (used by SMPV next iteration)
#pragma unroll
      for (int kh = 0; kh < 2; ++kh)
#pragma unroll
        for (int cf = 0; cf < 4; ++cf) {
          int row = cf * 16 + qi;
          vf[kh][cf] = *(const s16x8*)((const char*)&Vl[cur][0] + row * 128 + ((((kh << 2) | g) ^ (row & 7)) << 4));
        }
    }
    __syncthreads();
    cur ^= 1;
  }
  if (qt == smax) SMPV();               // long-tile waves: finish last tile

  float l_run = l0 + l1;
  l_run += __shfl_xor(l_run, 16);
  l_run += __shfl_xor(l_run, 32);
  float inv = 1.0f / l_run;
#pragma unroll
  for (int cf = 0; cf < 4; ++cf) {
    int col = h * 64 + cf * 16 + g * 4;
    int chunk = col >> 3;
    int chs = (chunk & ~7) | ((chunk & 7) ^ (qg & 7));
    char* ob = (char*)o + (size_t)qg * 2048 + (chs << 4) + ((g & 1) << 3);
    *(unsigned int*)ob = cvtpk(acc[cf][0] * inv, acc[cf][1] * inv);
    *(unsigned int*)(ob + 4) = cvtpk(acc[cf][2] * inv, acc[cf][3] * inv);
  }
}

extern "C" void kernel_launch(void* const* d_in, const int* in_sizes, int n_in,
                              void* d_out, int out_size, void* d_ws, size_t ws_size,
                              hipStream_t stream) {
  const float* hs   = (const float*)d_in[0];
  const float* cosb = (const float*)d_in[1];
  const float* sinb = (const float*)d_in[2];
  const float* Wq   = (const float*)d_in[3];
  const float* Wk   = (const float*)d_in[4];
  const float* Wv   = (const float*)d_in[5];
  const float* Wo   = (const float*)d_in[6];
  const float* qw   = (const float*)d_in[7];
  const float* kw   = (const float*)d_in[8];
  char* ws = (char*)d_ws;
  unsigned short* hs_swz = (unsigned short*)(ws + OFF_HS);
  unsigned short* wqkv   = (unsigned short*)(ws + OFF_WQKV);
  unsigned short* wo_t   = (unsigned short*)(ws + OFF_WO);
  float*          qkv    = (float*)(ws + OFF_QKV);
  unsigned short* qbf    = (unsigned short*)(ws + OFF_Q);
  unsigned short* kbf    = (unsigned short*)(ws + OFF_K);
  unsigned short* vtb    = (unsigned short*)(ws + OFF_VT);
  unsigned short* obf    = (unsigned short*)(ws + OFF_O);

  k_convert_hs<<<2048, 256, 0, stream>>>(hs, hs_swz);
  k_convert_w_all<<<1280, 256, 0, stream>>>(Wq, Wk, Wv, Wo, wqkv, wo_t);
  k_gemm<<<dim3(12, 32), 512, 0, stream>>>(hs_swz, wqkv, qkv, 4096, 1536, 1024);
  k_prep<<<20480, 256, 0, stream>>>(qkv, cosb, sinb, qw, kw, qbf, kbf);
  k_vT<<<dim3(64, 4), 256, 0, stream>>>(qkv, vtb);
  k_attn<<<512, 512, 0, stream>>>(qbf, kbf, vtb, obf);
  k_gemm<<<dim3(8, 32), 512, 0, stream>>>(obf, wo_t, (float*)d_out, 4096, 1024, 1024);
}

// Round 8
// 169.020 us; speedup vs baseline: 1.7898x; 1.0868x over previous
//
#include <hip/hip_runtime.h>
#include <stdint.h>

#define TT 4096
#define HIDD 1024

typedef __attribute__((ext_vector_type(4))) float f32x4;
typedef __attribute__((ext_vector_type(8))) short s16x8;

static constexpr float kEps = 1e-6f;
static constexpr float kCsc = 0.125f * 1.44269504088896f;  // scale * log2(e), folded into q

// ---- workspace layout (bytes) ----
static constexpr size_t OFF_HS   = 0;          // bf16 hs swz   [4096][1024]  8 MB
static constexpr size_t OFF_WQKV = 8388608;    // bf16 WqkvT swz [1536][1024] 3 MB
static constexpr size_t OFF_WO   = 11534336;   // bf16 WoT swz  [1024][1024]  2 MB
static constexpr size_t OFF_QKV  = 13631488;   // f32 qkv       [4096][1536] 24 MB
static constexpr size_t OFF_Q    = 0;          // bf16 q  [16][4096][64] (reuse HS)
static constexpr size_t OFF_K    = 8388608;    // bf16 k swz [4][4096][64] (reuse WQKV)
static constexpr size_t OFF_VT   = 38797312;   // bf16 vT swz [4][64][4096] 2 MB
static constexpr size_t OFF_O    = 13631488;   // bf16 attn-out swz [4096][1024] (reuse QKV)

__device__ __forceinline__ unsigned int pk_bf16(float a, float b) {
  union { float f; unsigned int u; } x, y;
  x.f = a; y.f = b;
  unsigned int lo = (x.u + 0x7fffu + ((x.u >> 16) & 1u)) >> 16;
  unsigned int hi = (y.u + 0x7fffu + ((y.u >> 16) & 1u)) >> 16;
  return (lo & 0xffffu) | (hi << 16);
}
__device__ __forceinline__ unsigned short bf16_1(float a) {
  union { float f; unsigned int u; } x; x.f = a;
  return (unsigned short)((x.u + 0x7fffu + ((x.u >> 16) & 1u)) >> 16);
}
__device__ __forceinline__ unsigned int cvtpk(float lo, float hi) {
  unsigned int r;
  asm("v_cvt_pk_bf16_f32 %0, %1, %2" : "=v"(r) : "v"(lo), "v"(hi));
  return r;
}
__device__ __forceinline__ void gload16(const void* g, void* l) {
  __builtin_amdgcn_global_load_lds(
      (const __attribute__((address_space(1))) unsigned int*)g,
      (__attribute__((address_space(3))) unsigned int*)l, 16, 0, 0);
}

// hs fp32 [T][1024] -> bf16 swizzled (16B chunk index XORed by row&7 within 64-elem groups)
__global__ void k_convert_hs(const float* __restrict__ hs, unsigned short* __restrict__ out) {
  int idx = blockIdx.x * 256 + threadIdx.x;  // T*128
  int t = idx >> 7, kc = idx & 127;
  const float4* src = (const float4*)(hs + (size_t)t * HIDD + kc * 8);
  float4 a = src[0], b = src[1];
  int kcs = (kc & ~7) | ((kc & 7) ^ (t & 7));
  uint4 w;
  w.x = pk_bf16(a.x, a.y); w.y = pk_bf16(a.z, a.w);
  w.z = pk_bf16(b.x, b.y); w.w = pk_bf16(b.z, b.w);
  *(uint4*)(out + (size_t)t * HIDD + kcs * 8) = w;
}

// All four weight matrices: fp32 [1024][ncols] -> bf16 W^T [ncols][1024] swizzled by n&7
__global__ void k_convert_w_all(const float* __restrict__ Wq, const float* __restrict__ Wk,
                                const float* __restrict__ Wv, const float* __restrict__ Wo,
                                unsigned short* __restrict__ wqkv, unsigned short* __restrict__ wo_t) {
  int b = blockIdx.x, tid = threadIdx.x;
  const float* W; unsigned short* outT; int nshift, idx;
  if (b < 512)      { W = Wq; outT = wqkv;                nshift = 10; idx = b * 256 + tid; }
  else if (b < 640) { W = Wk; outT = wqkv + 1024 * 1024;  nshift = 8;  idx = (b - 512) * 256 + tid; }
  else if (b < 768) { W = Wv; outT = wqkv + 1280 * 1024;  nshift = 8;  idx = (b - 640) * 256 + tid; }
  else              { W = Wo; outT = wo_t;                nshift = 10; idx = (b - 768) * 256 + tid; }
  int ncols = 1 << nshift;
  int kc = idx >> nshift, n = idx & (ncols - 1);
  float v[8];
#pragma unroll
  for (int e = 0; e < 8; ++e) v[e] = W[(size_t)(kc * 8 + e) * ncols + n];
  int kcs = (kc & ~7) | ((kc & 7) ^ (n & 7));
  uint4 w;
  w.x = pk_bf16(v[0], v[1]); w.y = pk_bf16(v[2], v[3]);
  w.z = pk_bf16(v[4], v[5]); w.w = pk_bf16(v[6], v[7]);
  *(uint4*)(outT + (size_t)n * HIDD + kcs * 8) = w;
}

// C[M][N] = A[M][K] * Bt[N][K]^T ; A,Bt bf16 chunk-swizzled; C fp32.
// 128x64 tile, BK=64, 4 waves (2x2 of 64x32), dbuf LDS (48KB -> 3 blocks/CU).
__global__ __launch_bounds__(256) void k_gemm(const unsigned short* __restrict__ A,
                                              const unsigned short* __restrict__ Bt,
                                              float* __restrict__ C, int M, int N, int K) {
  __shared__ __attribute__((aligned(16))) unsigned short As[2][128 * 64];
  __shared__ __attribute__((aligned(16))) unsigned short Bs[2][64 * 64];
  const int tid = threadIdx.x;
  const int m0 = blockIdx.y * 128, n0 = blockIdx.x * 64;
  const int wid = tid >> 6, lane = tid & 63;
  const int g = lane >> 4, qi = lane & 15;
  const int wr = wid >> 1, wc = wid & 1;
  const int srow = lane >> 3, schk = lane & 7;
  f32x4 acc[4][2] = {};
  const int nkt = K >> 6;

  auto STAGE = [&](int b, int k0) {
#pragma unroll
    for (int j = 0; j < 4; ++j) {
      int ra = j * 32 + wid * 8 + srow;
      gload16(A + (size_t)(m0 + ra) * K + k0 + schk * 8,
              (char*)&As[b][0] + j * 4096 + (wid << 10));
    }
#pragma unroll
    for (int j = 0; j < 2; ++j) {
      int rb = j * 32 + wid * 8 + srow;
      gload16(Bt + (size_t)(n0 + rb) * K + k0 + schk * 8,
              (char*)&Bs[b][0] + j * 4096 + (wid << 10));
    }
  };

  STAGE(0, 0);
  __syncthreads();
  int cur = 0;
  for (int kt = 0; kt < nkt; ++kt) {
    if (kt + 1 < nkt) STAGE(cur ^ 1, (kt + 1) << 6);
#pragma unroll
    for (int kh = 0; kh < 2; ++kh) {
      s16x8 af[4], bq[2];
#pragma unroll
      for (int i = 0; i < 4; ++i) {
        int rA = wr * 64 + i * 16 + qi;
        af[i] = *(const s16x8*)((const char*)&As[cur][0] + rA * 128 + ((((kh << 2) | g) ^ (rA & 7)) << 4));
      }
#pragma unroll
      for (int jn = 0; jn < 2; ++jn) {
        int rB = wc * 32 + jn * 16 + qi;
        bq[jn] = *(const s16x8*)((const char*)&Bs[cur][0] + rB * 128 + ((((kh << 2) | g) ^ (rB & 7)) << 4));
      }
      __builtin_amdgcn_s_setprio(1);
#pragma unroll
      for (int i = 0; i < 4; ++i)
#pragma unroll
        for (int jn = 0; jn < 2; ++jn)
          acc[i][jn] = __builtin_amdgcn_mfma_f32_16x16x32_bf16(af[i], bq[jn], acc[i][jn], 0, 0, 0);
      __builtin_amdgcn_s_setprio(0);
    }
    __syncthreads();
    cur ^= 1;
  }
#pragma unroll
  for (int i = 0; i < 4; ++i)
#pragma unroll
    for (int jn = 0; jn < 2; ++jn) {
      int row = m0 + wr * 64 + i * 16 + g * 4;
      int col = n0 + wc * 32 + jn * 16 + qi;
#pragma unroll
      for (int r = 0; r < 4; ++r)
        C[(size_t)(row + r) * N + col] = acc[i][jn][r];
    }
}

// RMSNorm + RoPE for q (slots 0..15) and k (slots 16..19). One wave per (t,slot).
// q pre-scaled by 0.125*log2(e) so attention scores are directly in exp2 domain.
__global__ void k_prep(const float* __restrict__ qkv, const float* __restrict__ cosb,
                       const float* __restrict__ sinb, const float* __restrict__ qw,
                       const float* __restrict__ kw, unsigned short* __restrict__ qo,
                       unsigned short* __restrict__ ko) {
  int rowid = blockIdx.x * 4 + (threadIdx.x >> 6);
  int lane = threadIdx.x & 63;
  int t = rowid / 20, slot = rowid % 20;
  float x = qkv[(size_t)t * 1536 + slot * 64 + lane];
  float ss = x * x;
#pragma unroll
  for (int off = 32; off; off >>= 1) ss += __shfl_xor(ss, off);
  float n = x * rsqrtf(ss * (1.0f / 64.0f) + kEps);
  n *= (slot < 16) ? qw[lane] : kw[lane];
  float c = cosb[t * 32 + (lane & 31)];
  float s = sinb[t * 32 + (lane & 31)];
  float other = __shfl_xor(n, 32);
  float r = (lane < 32) ? (n * c - other * s) : (other * s + n * c);
  if (slot < 16) {
    unsigned short b = bf16_1(r * kCsc);
    qo[((size_t)slot * TT + t) * 64 + lane] = b;   // linear [h][t][d]
  } else {
    unsigned short b = bf16_1(r);
    int hv = slot - 16;
    int d = (((lane >> 3) ^ (t & 7)) << 3) | (lane & 7);  // swizzle chunks by t&7
    ko[((size_t)hv * TT + t) * 64 + d] = b;
  }
}

// v: qkv fp32 [t][1280+hv*64+d] -> bf16 vT [hv][d][t], t-chunks swizzled by d&7
__global__ void k_vT(const float* __restrict__ qkv, unsigned short* __restrict__ vt) {
  __shared__ float tile[64][65];
  int t0 = blockIdx.x * 64, hv = blockIdx.y, tid = threadIdx.x;
  int cc = tid & 63, rr0 = tid >> 6;
#pragma unroll
  for (int i = 0; i < 16; ++i) {
    int r = rr0 * 16 + i;
    tile[r][cc] = qkv[(size_t)(t0 + r) * 1536 + 1280 + hv * 64 + cc];
  }
  __syncthreads();
#pragma unroll
  for (int jj = 0; jj < 2; ++jj) {
    int idx = jj * 256 + tid;
    int d = idx >> 3, tc = idx & 7;
    uint4 w;
    w.x = pk_bf16(tile[tc * 8 + 0][d], tile[tc * 8 + 1][d]);
    w.y = pk_bf16(tile[tc * 8 + 2][d], tile[tc * 8 + 3][d]);
    w.z = pk_bf16(tile[tc * 8 + 4][d], tile[tc * 8 + 5][d]);
    w.w = pk_bf16(tile[tc * 8 + 6][d], tile[tc * 8 + 7][d]);
    int tcs = tc ^ (d & 7);
    *(uint4*)(vt + ((size_t)hv * 64 + d) * TT + t0 + tcs * 8) = w;
  }
}

// Flash attention, causal GQA. One 64-row q-tile per block; 2 waves x 32 q-rows.
// Each wave computes TWO 16-row MFMA sets sharing one kf/vf LDS read (40% less
// LDS traffic/flop than 16q waves). Staged dbuf K/V (one barrier/step), fixed-max
// exp2 softmax, P via wave-private swizzled LDS. 1024 blocks (16h x 64 tiles),
// 40KB LDS -> exactly 4 blocks/CU; longest-first; XCD-chunked (1 KV group/XCD).
__global__ __launch_bounds__(128, 2) void k_attn(const unsigned short* __restrict__ q,
                                                 const unsigned short* __restrict__ kk,
                                                 const unsigned short* __restrict__ vt,
                                                 unsigned short* __restrict__ o) {
  __shared__ __attribute__((aligned(16))) unsigned short Kl[2][64 * 64];
  __shared__ __attribute__((aligned(16))) unsigned short Vl[2][64 * 64];
  __shared__ __attribute__((aligned(16))) unsigned short Pl[2][2048];
  const int tid = threadIdx.x;
  const int wid = tid >> 6, lane = tid & 63, g = lane >> 4, qi = lane & 15;
  const int bid = blockIdx.x;
  const int xcd = bid & 7, j = bid >> 3;           // j in [0,128)
  const int head = xcd * 2 + (j & 1);              // 2 heads per XCD
  const int qt = 63 - (j >> 1);                    // longest tiles first
  const int hv = head >> 2;
  char* pb = (char*)&Pl[wid][0];
  const int srow = lane >> 3, schk8 = (lane & 7) * 8;

  auto STAGE = [&](int b, int s) {
    const int kv0 = s * 64;
#pragma unroll
    for (int jj = 0; jj < 4; ++jj) {
      int r = jj * 16 + wid * 8 + srow;
      gload16(kk + ((size_t)hv * TT + kv0 + r) * 64 + schk8,
              (char*)&Kl[b][0] + jj * 2048 + (wid << 10));
      gload16(vt + ((size_t)hv * 64 + r) * TT + kv0 + schk8,
              (char*)&Vl[b][0] + jj * 2048 + (wid << 10));
    }
  };

  const int qg0 = qt * 64 + wid * 32 + qi;         // set 0 q-row
  s16x8 qf[2][2];
#pragma unroll
  for (int t = 0; t < 2; ++t)
#pragma unroll
    for (int kh = 0; kh < 2; ++kh)
      qf[t][kh] = *(const s16x8*)(q + ((size_t)head * TT + qg0 + t * 16) * 64 + kh * 32 + g * 8);
  f32x4 acc[2][4] = {};
  float lsum[2] = {0.0f, 0.0f};

  STAGE(0, 0);
  __syncthreads();
  int cur = 0;
  for (int s = 0; s <= qt; ++s) {
    if (s < qt) STAGE(cur ^ 1, s + 1);
    const int kv0 = s * 64;
    // K fragments once, reused by both q-sets
    s16x8 kf[2][4];
#pragma unroll
    for (int kh = 0; kh < 2; ++kh)
#pragma unroll
      for (int cf = 0; cf < 4; ++cf) {
        int row = cf * 16 + qi;
        kf[kh][cf] = *(const s16x8*)((const char*)&Kl[cur][0] + row * 128 + ((((kh << 2) | g) ^ (qi & 7)) << 4));
      }
    f32x4 sacc[2][4] = {};
#pragma unroll
    for (int kh = 0; kh < 2; ++kh) {
      __builtin_amdgcn_s_setprio(1);
#pragma unroll
      for (int cf = 0; cf < 4; ++cf) {
        sacc[0][cf] = __builtin_amdgcn_mfma_f32_16x16x32_bf16(kf[kh][cf], qf[0][kh], sacc[0][cf], 0, 0, 0);
        sacc[1][cf] = __builtin_amdgcn_mfma_f32_16x16x32_bf16(kf[kh][cf], qf[1][kh], sacc[1][cf], 0, 0, 0);
      }
      __builtin_amdgcn_s_setprio(0);
    }
    // fixed-max softmax (scores bounded by RMSNorm); P^T write [q][kv] swizzled
    const bool diag = (s == qt);
#pragma unroll
    for (int t = 0; t < 2; ++t) {
      float pv[16];
      const int qg = qg0 + t * 16;
      if (diag) {
#pragma unroll
        for (int cf = 0; cf < 4; ++cf)
#pragma unroll
          for (int r = 0; r < 4; ++r) {
            float v = sacc[t][cf][r];
            pv[cf * 4 + r] = ((kv0 + cf * 16 + g * 4 + r) > qg) ? -1e30f : v;
          }
      } else {
#pragma unroll
        for (int cf = 0; cf < 4; ++cf)
#pragma unroll
          for (int r = 0; r < 4; ++r) pv[cf * 4 + r] = sacc[t][cf][r];
      }
      float l0 = 0.0f, l1 = 0.0f;
#pragma unroll
      for (int i = 0; i < 8; ++i) {
        float e0 = exp2f(pv[2 * i]), e1 = exp2f(pv[2 * i + 1]);
        pv[2 * i] = e0; pv[2 * i + 1] = e1;
        l0 += e0; l1 += e1;
      }
      lsum[t] += l0 + l1;
      const int qrow = t * 16 + qi;
#pragma unroll
      for (int cf = 0; cf < 4; ++cf) {
        int chunk = cf * 2 + (g >> 1);
        int base = qrow * 128 + ((chunk ^ (qi & 7)) << 4) + ((g & 1) << 3);
        uint2 pw;
        pw.x = cvtpk(pv[cf * 4 + 0], pv[cf * 4 + 1]);
        pw.y = cvtpk(pv[cf * 4 + 2], pv[cf * 4 + 3]);
        *(uint2*)(pb + base) = pw;
      }
    }
    // PV: vf once, P fragments per set
#pragma unroll
    for (int kh = 0; kh < 2; ++kh) {
      s16x8 vf[4];
#pragma unroll
      for (int cf = 0; cf < 4; ++cf) {
        int row = cf * 16 + qi;
        vf[cf] = *(const s16x8*)((const char*)&Vl[cur][0] + row * 128 + ((((kh << 2) | g) ^ (qi & 7)) << 4));
      }
      s16x8 pf0 = *(const s16x8*)(pb + (0 * 16 + qi) * 128 + ((((kh << 2) | g) ^ (qi & 7)) << 4));
      s16x8 pf1 = *(const s16x8*)(pb + (1 * 16 + qi) * 128 + ((((kh << 2) | g) ^ (qi & 7)) << 4));
      __builtin_amdgcn_s_setprio(1);
#pragma unroll
      for (int cf = 0; cf < 4; ++cf) {
        acc[0][cf] = __builtin_amdgcn_mfma_f32_16x16x32_bf16(vf[cf], pf0, acc[0][cf], 0, 0, 0);
        acc[1][cf] = __builtin_amdgcn_mfma_f32_16x16x32_bf16(vf[cf], pf1, acc[1][cf], 0, 0, 0);
      }
      __builtin_amdgcn_s_setprio(0);
    }
    __syncthreads();
    cur ^= 1;
  }
#pragma unroll
  for (int t = 0; t < 2; ++t) {
    float l_run = lsum[t];
    l_run += __shfl_xor(l_run, 16);
    l_run += __shfl_xor(l_run, 32);
    float inv = 1.0f / l_run;
    const int qg = qg0 + t * 16;
#pragma unroll
    for (int cf = 0; cf < 4; ++cf) {
      int col = head * 64 + cf * 16 + g * 4;
      int chunk = col >> 3;
      int chs = (chunk & ~7) | ((chunk & 7) ^ (qg & 7));
      char* ob = (char*)o + (size_t)qg * 2048 + (chs << 4) + ((g & 1) << 3);
      *(unsigned int*)ob = cvtpk(acc[t][cf][0] * inv, acc[t][cf][1] * inv);
      *(unsigned int*)(ob + 4) = cvtpk(acc[t][cf][2] * inv, acc[t][cf][3] * inv);
    }
  }
}

extern "C" void kernel_launch(void* const* d_in, const int* in_sizes, int n_in,
                              void* d_out, int out_size, void* d_ws, size_t ws_size,
                              hipStream_t stream) {
  const float* hs   = (const float*)d_in[0];
  const float* cosb = (const float*)d_in[1];
  const float* sinb = (const float*)d_in[2];
  const float* Wq   = (const float*)d_in[3];
  const float* Wk   = (const float*)d_in[4];
  const float* Wv   = (const float*)d_in[5];
  const float* Wo   = (const float*)d_in[6];
  const float* qw   = (const float*)d_in[7];
  const float* kw   = (const float*)d_in[8];
  char* ws = (char*)d_ws;
  unsigned short* hs_swz = (unsigned short*)(ws + OFF_HS);
  unsigned short* wqkv   = (unsigned short*)(ws + OFF_WQKV);
  unsigned short* wo_t   = (unsigned short*)(ws + OFF_WO);
  float*          qkv    = (float*)(ws + OFF_QKV);
  unsigned short* qbf    = (unsigned short*)(ws + OFF_Q);
  unsigned short* kbf    = (unsigned short*)(ws + OFF_K);
  unsigned short* vtb    = (unsigned short*)(ws + OFF_VT);
  unsigned short* obf    = (unsigned short*)(ws + OFF_O);

  k_convert_hs<<<2048, 256, 0, stream>>>(hs, hs_swz);
  k_convert_w_all<<<1280, 256, 0, stream>>>(Wq, Wk, Wv, Wo, wqkv, wo_t);
  k_gemm<<<dim3(24, 32), 256, 0, stream>>>(hs_swz, wqkv, qkv, 4096, 1536, 1024);
  k_prep<<<20480, 256, 0, stream>>>(qkv, cosb, sinb, qw, kw, qbf, kbf);
  k_vT<<<dim3(64, 4), 256, 0, stream>>>(qkv, vtb);
  k_attn<<<1024, 128, 0, stream>>>(qbf, kbf, vtb, obf);
  k_gemm<<<dim3(16, 32), 256, 0, stream>>>(obf, wo_t, (float*)d_out, 4096, 1024, 1024);
}

// Round 9
// 140.950 us; speedup vs baseline: 2.1462x; 1.1991x over previous
//
#include <hip/hip_runtime.h>
#include <stdint.h>

#define TT 4096
#define HIDD 1024

typedef __attribute__((ext_vector_type(4))) float f32x4;
typedef __attribute__((ext_vector_type(8))) short s16x8;

static constexpr float kEps = 1e-6f;
static constexpr float kCsc = 0.125f * 1.44269504088896f;  // scale * log2(e), folded into q

// ---- workspace layout (bytes) ----
static constexpr size_t OFF_HS   = 0;          // bf16 hs swz   [4096][1024]  8 MB
static constexpr size_t OFF_WQKV = 8388608;    // bf16 WqkvT swz [1536][1024] 3 MB
static constexpr size_t OFF_WO   = 11534336;   // bf16 WoT swz  [1024][1024]  2 MB
static constexpr size_t OFF_QKV  = 13631488;   // f32 qkv       [4096][1536] 24 MB
static constexpr size_t OFF_Q    = 0;          // bf16 q  [16][4096][64] (reuse HS)
static constexpr size_t OFF_K    = 8388608;    // bf16 k swz [4][4096][64] (reuse WQKV)
static constexpr size_t OFF_VT   = 38797312;   // bf16 vT swz [4][64][4096] 2 MB
static constexpr size_t OFF_O    = 13631488;   // bf16 attn-out swz [4096][1024] (reuse QKV)

__device__ __forceinline__ unsigned int pk_bf16(float a, float b) {
  union { float f; unsigned int u; } x, y;
  x.f = a; y.f = b;
  unsigned int lo = (x.u + 0x7fffu + ((x.u >> 16) & 1u)) >> 16;
  unsigned int hi = (y.u + 0x7fffu + ((y.u >> 16) & 1u)) >> 16;
  return (lo & 0xffffu) | (hi << 16);
}
__device__ __forceinline__ unsigned short bf16_1(float a) {
  union { float f; unsigned int u; } x; x.f = a;
  return (unsigned short)((x.u + 0x7fffu + ((x.u >> 16) & 1u)) >> 16);
}
__device__ __forceinline__ unsigned int cvtpk(float lo, float hi) {
  unsigned int r;
  asm("v_cvt_pk_bf16_f32 %0, %1, %2" : "=v"(r) : "v"(lo), "v"(hi));
  return r;
}
__device__ __forceinline__ void gload16(const void* g, void* l) {
  __builtin_amdgcn_global_load_lds(
      (const __attribute__((address_space(1))) unsigned int*)g,
      (__attribute__((address_space(3))) unsigned int*)l, 16, 0, 0);
}

// hs fp32 [T][1024] -> bf16 swizzled (16B chunk index XORed by row&7 within 64-elem groups)
__global__ void k_convert_hs(const float* __restrict__ hs, unsigned short* __restrict__ out) {
  int idx = blockIdx.x * 256 + threadIdx.x;  // T*128
  int t = idx >> 7, kc = idx & 127;
  const float4* src = (const float4*)(hs + (size_t)t * HIDD + kc * 8);
  float4 a = src[0], b = src[1];
  int kcs = (kc & ~7) | ((kc & 7) ^ (t & 7));
  uint4 w;
  w.x = pk_bf16(a.x, a.y); w.y = pk_bf16(a.z, a.w);
  w.z = pk_bf16(b.x, b.y); w.w = pk_bf16(b.z, b.w);
  *(uint4*)(out + (size_t)t * HIDD + kcs * 8) = w;
}

// All four weight matrices: fp32 [1024][ncols] -> bf16 W^T [ncols][1024] swizzled by n&7
__global__ void k_convert_w_all(const float* __restrict__ Wq, const float* __restrict__ Wk,
                                const float* __restrict__ Wv, const float* __restrict__ Wo,
                                unsigned short* __restrict__ wqkv, unsigned short* __restrict__ wo_t) {
  int b = blockIdx.x, tid = threadIdx.x;
  const float* W; unsigned short* outT; int nshift, idx;
  if (b < 512)      { W = Wq; outT = wqkv;                nshift = 10; idx = b * 256 + tid; }
  else if (b < 640) { W = Wk; outT = wqkv + 1024 * 1024;  nshift = 8;  idx = (b - 512) * 256 + tid; }
  else if (b < 768) { W = Wv; outT = wqkv + 1280 * 1024;  nshift = 8;  idx = (b - 640) * 256 + tid; }
  else              { W = Wo; outT = wo_t;                nshift = 10; idx = (b - 768) * 256 + tid; }
  int ncols = 1 << nshift;
  int kc = idx >> nshift, n = idx & (ncols - 1);
  float v[8];
#pragma unroll
  for (int e = 0; e < 8; ++e) v[e] = W[(size_t)(kc * 8 + e) * ncols + n];
  int kcs = (kc & ~7) | ((kc & 7) ^ (n & 7));
  uint4 w;
  w.x = pk_bf16(v[0], v[1]); w.y = pk_bf16(v[2], v[3]);
  w.z = pk_bf16(v[4], v[5]); w.w = pk_bf16(v[6], v[7]);
  *(uint4*)(outT + (size_t)n * HIDD + kcs * 8) = w;
}

// C[M][N] = A[M][K] * Bt[N][K]^T ; A,Bt bf16 chunk-swizzled; C fp32.
// 128x64 tile, BK=64, 4 waves (2x2 of 64x32), dbuf LDS (48KB -> 3 blocks/CU).
__global__ __launch_bounds__(256) void k_gemm(const unsigned short* __restrict__ A,
                                              const unsigned short* __restrict__ Bt,
                                              float* __restrict__ C, int M, int N, int K) {
  __shared__ __attribute__((aligned(16))) unsigned short As[2][128 * 64];
  __shared__ __attribute__((aligned(16))) unsigned short Bs[2][64 * 64];
  const int tid = threadIdx.x;
  const int m0 = blockIdx.y * 128, n0 = blockIdx.x * 64;
  const int wid = tid >> 6, lane = tid & 63;
  const int g = lane >> 4, qi = lane & 15;
  const int wr = wid >> 1, wc = wid & 1;
  const int srow = lane >> 3, schk = lane & 7;
  f32x4 acc[4][2] = {};
  const int nkt = K >> 6;

  auto STAGE = [&](int b, int k0) {
#pragma unroll
    for (int j = 0; j < 4; ++j) {
      int ra = j * 32 + wid * 8 + srow;
      gload16(A + (size_t)(m0 + ra) * K + k0 + schk * 8,
              (char*)&As[b][0] + j * 4096 + (wid << 10));
    }
#pragma unroll
    for (int j = 0; j < 2; ++j) {
      int rb = j * 32 + wid * 8 + srow;
      gload16(Bt + (size_t)(n0 + rb) * K + k0 + schk * 8,
              (char*)&Bs[b][0] + j * 4096 + (wid << 10));
    }
  };

  STAGE(0, 0);
  __syncthreads();
  int cur = 0;
  for (int kt = 0; kt < nkt; ++kt) {
    if (kt + 1 < nkt) STAGE(cur ^ 1, (kt + 1) << 6);
#pragma unroll
    for (int kh = 0; kh < 2; ++kh) {
      s16x8 af[4], bq[2];
#pragma unroll
      for (int i = 0; i < 4; ++i) {
        int rA = wr * 64 + i * 16 + qi;
        af[i] = *(const s16x8*)((const char*)&As[cur][0] + rA * 128 + ((((kh << 2) | g) ^ (rA & 7)) << 4));
      }
#pragma unroll
      for (int jn = 0; jn < 2; ++jn) {
        int rB = wc * 32 + jn * 16 + qi;
        bq[jn] = *(const s16x8*)((const char*)&Bs[cur][0] + rB * 128 + ((((kh << 2) | g) ^ (rB & 7)) << 4));
      }
      __builtin_amdgcn_s_setprio(1);
#pragma unroll
      for (int i = 0; i < 4; ++i)
#pragma unroll
        for (int jn = 0; jn < 2; ++jn)
          acc[i][jn] = __builtin_amdgcn_mfma_f32_16x16x32_bf16(af[i], bq[jn], acc[i][jn], 0, 0, 0);
      __builtin_amdgcn_s_setprio(0);
    }
    __syncthreads();
    cur ^= 1;
  }
#pragma unroll
  for (int i = 0; i < 4; ++i)
#pragma unroll
    for (int jn = 0; jn < 2; ++jn) {
      int row = m0 + wr * 64 + i * 16 + g * 4;
      int col = n0 + wc * 32 + jn * 16 + qi;
#pragma unroll
      for (int r = 0; r < 4; ++r)
        C[(size_t)(row + r) * N + col] = acc[i][jn][r];
    }
}

// RMSNorm + RoPE for q (slots 0..15) and k (slots 16..19). One wave per (t,slot).
// q pre-scaled by 0.125*log2(e) so attention scores are directly in exp2 domain.
__global__ void k_prep(const float* __restrict__ qkv, const float* __restrict__ cosb,
                       const float* __restrict__ sinb, const float* __restrict__ qw,
                       const float* __restrict__ kw, unsigned short* __restrict__ qo,
                       unsigned short* __restrict__ ko) {
  int rowid = blockIdx.x * 4 + (threadIdx.x >> 6);
  int lane = threadIdx.x & 63;
  int t = rowid / 20, slot = rowid % 20;
  float x = qkv[(size_t)t * 1536 + slot * 64 + lane];
  float ss = x * x;
#pragma unroll
  for (int off = 32; off; off >>= 1) ss += __shfl_xor(ss, off);
  float n = x * rsqrtf(ss * (1.0f / 64.0f) + kEps);
  n *= (slot < 16) ? qw[lane] : kw[lane];
  float c = cosb[t * 32 + (lane & 31)];
  float s = sinb[t * 32 + (lane & 31)];
  float other = __shfl_xor(n, 32);
  float r = (lane < 32) ? (n * c - other * s) : (other * s + n * c);
  if (slot < 16) {
    unsigned short b = bf16_1(r * kCsc);
    qo[((size_t)slot * TT + t) * 64 + lane] = b;   // linear [h][t][d]
  } else {
    unsigned short b = bf16_1(r);
    int hv = slot - 16;
    int d = (((lane >> 3) ^ (t & 7)) << 3) | (lane & 7);  // swizzle chunks by t&7
    ko[((size_t)hv * TT + t) * 64 + d] = b;
  }
}

// v: qkv fp32 [t][1280+hv*64+d] -> bf16 vT [hv][d][t], t-chunks swizzled by d&7
__global__ void k_vT(const float* __restrict__ qkv, unsigned short* __restrict__ vt) {
  __shared__ float tile[64][65];
  int t0 = blockIdx.x * 64, hv = blockIdx.y, tid = threadIdx.x;
  int cc = tid & 63, rr0 = tid >> 6;
#pragma unroll
  for (int i = 0; i < 16; ++i) {
    int r = rr0 * 16 + i;
    tile[r][cc] = qkv[(size_t)(t0 + r) * 1536 + 1280 + hv * 64 + cc];
  }
  __syncthreads();
#pragma unroll
  for (int jj = 0; jj < 2; ++jj) {
    int idx = jj * 256 + tid;
    int d = idx >> 3, tc = idx & 7;
    uint4 w;
    w.x = pk_bf16(tile[tc * 8 + 0][d], tile[tc * 8 + 1][d]);
    w.y = pk_bf16(tile[tc * 8 + 2][d], tile[tc * 8 + 3][d]);
    w.z = pk_bf16(tile[tc * 8 + 4][d], tile[tc * 8 + 5][d]);
    w.w = pk_bf16(tile[tc * 8 + 6][d], tile[tc * 8 + 7][d]);
    int tcs = tc ^ (d & 7);
    *(uint4*)(vt + ((size_t)hv * 64 + d) * TT + t0 + tcs * 8) = w;
  }
}

// Flash attention, causal GQA — the R5 best-measured configuration (78.6us).
// 512 threads = 8 waves: waves 0-3 own q-tile i0, waves 4-7 own q-tile 63-i0; both
// share the same K/V double-buffered staging. FIXED-MAX exp2 softmax (RMSNorm bounds
// |q.k*scale*log2e| <= 11.6 -> P = exp2(s) directly); normalize by l at the end.
// LDS padded to 56KB so exactly 2 blocks/CU -> even packing of 512 uniform blocks.
__global__ __launch_bounds__(512) void k_attn(const unsigned short* __restrict__ q,
                                              const unsigned short* __restrict__ kk,
                                              const unsigned short* __restrict__ vt,
                                              unsigned short* __restrict__ o) {
  __shared__ __attribute__((aligned(16))) unsigned short Kl[2][64 * 64];
  __shared__ __attribute__((aligned(16))) unsigned short Vl[2][64 * 64];
  __shared__ __attribute__((aligned(16))) unsigned short Pl[8][1536];  // 1024 used + pad -> 56KB total
  const int tid = threadIdx.x;
  const int bid = blockIdx.x;
  const int work = (bid & 7) * 64 + (bid >> 3);    // XCD-chunked: 2 heads per XCD
  const int h = work >> 5;
  const int i0 = work & 31;
  const int hv = h >> 2;
  const int wid = tid >> 6, lane = tid & 63, g = lane >> 4, qi = lane & 15;
  const int qt = (wid < 4) ? i0 : (63 - i0);       // per-wave q-tile
  const int smax = 63 - i0;
  char* pb = (char*)&Pl[wid][0];

  auto STAGE = [&](int b, int s) {
    const int kv0 = s * 64;
    const int r = wid * 8 + (lane >> 3), c8 = (lane & 7) * 8;
    gload16(kk + ((size_t)hv * TT + kv0 + r) * 64 + c8, (char*)&Kl[b][0] + (wid << 10));
    gload16(vt + ((size_t)hv * 64 + r) * TT + kv0 + c8, (char*)&Vl[b][0] + (wid << 10));
  };

  const int qg = qt * 64 + (wid & 3) * 16 + qi;
  s16x8 qf[2];
#pragma unroll
  for (int kh = 0; kh < 2; ++kh)
    qf[kh] = *(const s16x8*)(q + ((size_t)h * TT + qg) * 64 + kh * 32 + g * 8);
  f32x4 acc[4] = {};
  float l0 = 0.0f, l1 = 0.0f;

  STAGE(0, 0);
  __syncthreads();
  int cur = 0;
  for (int s = 0; s <= smax; ++s) {
    if (s < smax) STAGE(cur ^ 1, s + 1);
    if (s <= qt) {
      const int kv0 = s * 64;
      f32x4 sacc[4] = {};
#pragma unroll
      for (int kh = 0; kh < 2; ++kh) {
        s16x8 kf[4];
#pragma unroll
        for (int cf = 0; cf < 4; ++cf) {
          int row = cf * 16 + qi;
          kf[cf] = *(const s16x8*)((const char*)&Kl[cur][0] + row * 128 + ((((kh << 2) | g) ^ (row & 7)) << 4));
        }
        __builtin_amdgcn_s_setprio(1);
#pragma unroll
        for (int cf = 0; cf < 4; ++cf)
          sacc[cf] = __builtin_amdgcn_mfma_f32_16x16x32_bf16(kf[cf], qf[kh], sacc[cf], 0, 0, 0);
        __builtin_amdgcn_s_setprio(0);
      }
      // per-lane: q-row = qi (fixed), kv = kv0 + cf*16 + g*4 + r ; scores bounded,
      // fixed-max: P = exp2(s) directly.
      float pv[16];
      if (s == qt) {
#pragma unroll
        for (int cf = 0; cf < 4; ++cf)
#pragma unroll
          for (int r = 0; r < 4; ++r) {
            float v = sacc[cf][r];
            if ((kv0 + cf * 16 + g * 4 + r) > qg) v = -1e30f;
            pv[cf * 4 + r] = v;
          }
      } else {
#pragma unroll
        for (int cf = 0; cf < 4; ++cf)
#pragma unroll
          for (int r = 0; r < 4; ++r) pv[cf * 4 + r] = sacc[cf][r];
      }
#pragma unroll
      for (int i = 0; i < 8; ++i) {
        float e0 = exp2f(pv[2 * i]), e1 = exp2f(pv[2 * i + 1]);
        pv[2 * i] = e0; pv[2 * i + 1] = e1;
        l0 += e0; l1 += e1;
      }
      // P^T stored as [q][kv] (bf16, swizzled by q&7), one b64 write per cf
#pragma unroll
      for (int cf = 0; cf < 4; ++cf) {
        int chunk = cf * 2 + (g >> 1);
        int base = qi * 128 + ((chunk ^ (qi & 7)) << 4) + ((g & 1) << 3);
        uint2 pw;
        pw.x = cvtpk(pv[cf * 4 + 0], pv[cf * 4 + 1]);
        pw.y = cvtpk(pv[cf * 4 + 2], pv[cf * 4 + 3]);
        *(uint2*)(pb + base) = pw;
      }
#pragma unroll
      for (int kh = 0; kh < 2; ++kh) {
        s16x8 pf = *(const s16x8*)(pb + qi * 128 + ((((kh << 2) | g) ^ (qi & 7)) << 4));
        s16x8 vf[4];
#pragma unroll
        for (int cf = 0; cf < 4; ++cf) {
          int row = cf * 16 + qi;
          vf[cf] = *(const s16x8*)((const char*)&Vl[cur][0] + row * 128 + ((((kh << 2) | g) ^ (row & 7)) << 4));
        }
        __builtin_amdgcn_s_setprio(1);
#pragma unroll
        for (int cf = 0; cf < 4; ++cf)
          acc[cf] = __builtin_amdgcn_mfma_f32_16x16x32_bf16(vf[cf], pf, acc[cf], 0, 0, 0);
        __builtin_amdgcn_s_setprio(0);
      }
    }
    __syncthreads();
    cur ^= 1;
  }
  float l_run = l0 + l1;
  l_run += __shfl_xor(l_run, 16);
  l_run += __shfl_xor(l_run, 32);
  float inv = 1.0f / l_run;
#pragma unroll
  for (int cf = 0; cf < 4; ++cf) {
    int col = h * 64 + cf * 16 + g * 4;
    int chunk = col >> 3;
    int chs = (chunk & ~7) | ((chunk & 7) ^ (qg & 7));
    char* ob = (char*)o + (size_t)qg * 2048 + (chs << 4) + ((g & 1) << 3);
    *(unsigned int*)ob = cvtpk(acc[cf][0] * inv, acc[cf][1] * inv);
    *(unsigned int*)(ob + 4) = cvtpk(acc[cf][2] * inv, acc[cf][3] * inv);
  }
}

extern "C" void kernel_launch(void* const* d_in, const int* in_sizes, int n_in,
                              void* d_out, int out_size, void* d_ws, size_t ws_size,
                              hipStream_t stream) {
  const float* hs   = (const float*)d_in[0];
  const float* cosb = (const float*)d_in[1];
  const float* sinb = (const float*)d_in[2];
  const float* Wq   = (const float*)d_in[3];
  const float* Wk   = (const float*)d_in[4];
  const float* Wv   = (const float*)d_in[5];
  const float* Wo   = (const float*)d_in[6];
  const float* qw   = (const float*)d_in[7];
  const float* kw   = (const float*)d_in[8];
  char* ws = (char*)d_ws;
  unsigned short* hs_swz = (unsigned short*)(ws + OFF_HS);
  unsigned short* wqkv   = (unsigned short*)(ws + OFF_WQKV);
  unsigned short* wo_t   = (unsigned short*)(ws + OFF_WO);
  float*          qkv    = (float*)(ws + OFF_QKV);
  unsigned short* qbf    = (unsigned short*)(ws + OFF_Q);
  unsigned short* kbf    = (unsigned short*)(ws + OFF_K);
  unsigned short* vtb    = (unsigned short*)(ws + OFF_VT);
  unsigned short* obf    = (unsigned short*)(ws + OFF_O);

  k_convert_hs<<<2048, 256, 0, stream>>>(hs, hs_swz);
  k_convert_w_all<<<1280, 256, 0, stream>>>(Wq, Wk, Wv, Wo, wqkv, wo_t);
  k_gemm<<<dim3(24, 32), 256, 0, stream>>>(hs_swz, wqkv, qkv, 4096, 1536, 1024);
  k_prep<<<20480, 256, 0, stream>>>(qkv, cosb, sinb, qw, kw, qbf, kbf);
  k_vT<<<dim3(64, 4), 256, 0, stream>>>(qkv, vtb);
  k_attn<<<512, 512, 0, stream>>>(qbf, kbf, vtb, obf);
  k_gemm<<<dim3(16, 32), 256, 0, stream>>>(obf, wo_t, (float*)d_out, 4096, 1024, 1024);
}